// Round 7
// baseline (312.800 us; speedup 1.0000x reference)
//
#include <hip/hip_runtime.h>

// LocallyConnected2D: y[n,h,w] = relu(sum_{i,j} x[n,h+i,w+j]*W[h,w,i,j] + b[h,w])
// lane = batch n (N=64=wave). History:
//  R1: scalar (SMEM) weights -> lgkmcnt drains mixed with ds_read.
//  R2: f[12] local array -> scratch (223MB writes).
//  R3: VMEM uniform weights + full unroll -> hoist pressure -> spill.
//  R4: weights via LDS broadcast (full unroll) -> hoisted ds_reads, spill.
//  R5: manual cur/nxt prefetch + memory clobber -> arrays in scratch (1.78GB).
//  R6: sched_barrier(0x7) regions -> allocator catastrophe (3.68GB scratch).
//  R7: runtime r loop, weights as per-iter uniform VMEM loads. 284us.
//  R8: weights bulk-staged to LDS, 18 broadcast ds_read_b128/iter. 205us.
//  R9: weights global->VGPR pack, readlane+fma hot loop, XOR-swizzled x LDS,
//      H_T=4, 3 blocks/CU (12 waves). 172us.
//  R10/R11: register-array prefetch -> SPILLED (357us). Never again.
//  R12: global_load_lds DMA row-ring -> 274us (memory system idle; DMA
//      gather issue + vmcnt(0)/tile). Wide dumb burst wins.
//  R13: H_T=8, 512-thr, 64KB, 16 waves/CU. 176us, FETCH 214MB (-58MB) but
//      time FLAT and realized BW fell to 1.6TB/s -> NOT HBM-throughput-bound.
//      Per-SIMD VALU only ~21% busy; per-gen each pipe needs 11-15k cyc but
//      gen takes 54k: phases serialize, too few waves to overlap pipes.
//  R14 (this): raise TLP. H_T=12, 768-thread blocks (12 waves), TROWS=20,
//      LDS=80KB exact -> 2 blocks/CU = 24 waves/CU = 6/SIMD (+50% vs R13).
//      Staging amplification 2.0->1.67x. Everything else byte-identical.

#define H_IN 512
#define W_IN 512
#define H_OUT 504
#define W_OUT 504
#define W_T 8
#define H_T 12
#define TROWS (H_T + 8)       // 20 staged input rows
#define XF (TROWS * 1024)     // 20480 floats = 80 KB -> 2 blocks/CU (160KB exact)
#define NTX 63                // tiles in w
#define NTY 42                // tiles in h (504/12)
#define NBLK (NTX * NTY)      // 2646

__device__ __forceinline__ float readlane_f(float v, int l) {
    return __int_as_float(__builtin_amdgcn_readlane(__float_as_int(v), l));
}

__launch_bounds__(768, 6)
__global__ void lc2d_kernel(const float* __restrict__ x,
                            const float* __restrict__ weight,
                            const float* __restrict__ bias,
                            float* __restrict__ out) {
    __shared__ float lds[XF];   // x tile: [row][wq][ (n*4)^(wq*4) ] swizzled

    const int t    = threadIdx.x;
    const int lane = t & 63;          // batch index n (compute phase)
    const int wv   = t >> 6;          // wave 0..11

    // bijective XCD swizzle: consecutive swz (= ty-adjacent tiles sharing
    // 8 x-rows) map to the same XCD, concurrently -> L2 reuse.
    int swz;
    {
        const int bid = blockIdx.x;
        const int xcd = bid & 7, i = bid >> 3;
        const int q = NBLK >> 3, r = NBLK & 7;          // 330, 6
        swz = (xcd < r ? xcd * (q + 1)
                       : r * (q + 1) + (xcd - r) * q) + i;
    }
    const int ty = swz % NTY;
    const int tx = swz / NTY;
    const int h0 = ty * H_T;
    const int w0 = tx * W_T;

    // ---- stage x tile; thread t: wq = t&3, n = (t>>2)&63, rg = t>>8 (0..2)
    // rows rg, rg+3, ..., rg+18 (7 reps, mask row>=20). Coalesced 64B per
    // 4 threads. LDS float addr = row*1024 + wq*256 + (n*4 ^ wq*4).
    {
        const int wq = t & 3;
        const int n  = (t >> 2) & 63;
        const int rg = t >> 8;
        const float* gx = x + (size_t)n * (H_IN * W_IN)
                            + (size_t)h0 * W_IN + w0 + wq * 4;
        float* ld = &lds[wq * 256 + ((n * 4) ^ (wq * 4))];
        #pragma unroll
        for (int rep = 0; rep < 7; ++rep) {
            const int row = rg + rep * 3;
            if (row < TROWS) {
                const float4 v =
                    *reinterpret_cast<const float4*>(gx + (size_t)row * W_IN);
                *reinterpret_cast<float4*>(ld + row * 1024) = v;
            }
        }
    }

    // ---- weights: per-wave gather global -> 18 VGPRs, packed p = q*16 + rr
    // (q = k*9+tp in 0..71, rr = tap row, slots rr=9..15 padding).
    // nt loads: read-once stream, don't evict x from L2.
    float wpk[18];
    {
        const float* wb = weight + ((size_t)(h0 + wv) * W_OUT + w0) * 81;
        const int qb = lane >> 4;     // 0..3
        const int rr = lane & 15;
        #pragma unroll
        for (int d = 0; d < 18; ++d) {
            const int q  = 4 * d + qb;        // 0..71
            const int k  = q / 9;             // magic-mul
            const int tp = q - 9 * k;
            float v = 0.f;
            if (rr < 9) v = __builtin_nontemporal_load(wb + k * 81 + rr * 9 + tp);
            wpk[d] = v;
        }
    }

    __syncthreads();

    const int wvu = __builtin_amdgcn_readfirstlane(wv);
    const int h   = h0 + wvu;                      // this wave's output row

    float acc[W_T];
    {
        const float* bptr = bias + (size_t)h * W_OUT + w0;   // uniform: s_load
        #pragma unroll
        for (int k = 0; k < W_T; ++k) acc[k] = bptr[k];
    }

    // 4 swizzled x chunk pointers for this lane; row offset advances 1024/iter
    const float* xp0 = &lds[0 * 256 + ((lane * 4) ^ 0)  + wvu * 1024];
    const float* xp1 = &lds[1 * 256 + ((lane * 4) ^ 4)  + wvu * 1024];
    const float* xp2 = &lds[2 * 256 + ((lane * 4) ^ 8)  + wvu * 1024];
    const float* xp3 = &lds[3 * 256 + ((lane * 4) ^ 12) + wvu * 1024];

    #pragma unroll 1
    for (int r = 0; r < 9; ++r) {
        // x row (wvu + r): 16 floats/lane via 4 conflict-free ds_read_b128
        float xr[16];
        {
            const float4 v0 = *reinterpret_cast<const float4*>(xp0);
            const float4 v1 = *reinterpret_cast<const float4*>(xp1);
            const float4 v2 = *reinterpret_cast<const float4*>(xp2);
            const float4 v3 = *reinterpret_cast<const float4*>(xp3);
            xr[0]  = v0.x; xr[1]  = v0.y; xr[2]  = v0.z; xr[3]  = v0.w;
            xr[4]  = v1.x; xr[5]  = v1.y; xr[6]  = v1.z; xr[7]  = v1.w;
            xr[8]  = v2.x; xr[9]  = v2.y; xr[10] = v2.z; xr[11] = v2.w;
            xr[12] = v3.x; xr[13] = v3.y; xr[14] = v3.z; xr[15] = v3.w;
        }

        const int li0 = r;
        const int li1 = r + 16;
        const int li2 = r + 32;
        const int li3 = r + 48;

        #pragma unroll
        for (int tp = 0; tp < 9; ++tp) {
            #pragma unroll
            for (int k = 0; k < W_T; ++k) {
                const int q  = k * 9 + tp;          // compile-time
                const int qm = q & 3;
                const int li = (qm == 0) ? li0 : (qm == 1) ? li1
                             : (qm == 2) ? li2 : li3;
                const float w = readlane_f(wpk[q >> 2], li);
                acc[k] = fmaf(w, xr[k + tp], acc[k]);
            }
        }

        xp0 += 1024; xp1 += 1024; xp2 += 1024; xp3 += 1024;
    }

    // ---- epilogue: ReLU + regular stores (L2 write-combines; nt amplified
    // scattered writes 1.7x in R12) ----
    float* o = out + (size_t)lane * (H_OUT * W_OUT) + (size_t)h * W_OUT + w0;
    float4 s;
    s.x = fmaxf(acc[0], 0.f); s.y = fmaxf(acc[1], 0.f);
    s.z = fmaxf(acc[2], 0.f); s.w = fmaxf(acc[3], 0.f);
    *reinterpret_cast<float4*>(o) = s;
    s.x = fmaxf(acc[4], 0.f); s.y = fmaxf(acc[5], 0.f);
    s.z = fmaxf(acc[6], 0.f); s.w = fmaxf(acc[7], 0.f);
    *reinterpret_cast<float4*>(o + 4) = s;
}

extern "C" void kernel_launch(void* const* d_in, const int* in_sizes, int n_in,
                              void* d_out, int out_size, void* d_ws, size_t ws_size,
                              hipStream_t stream) {
    const float* x      = (const float*)d_in[0];
    const float* weight = (const float*)d_in[1];
    const float* bias   = (const float*)d_in[2];
    float* out          = (float*)d_out;

    dim3 grid(NBLK);
    dim3 block(768);
    lc2d_kernel<<<grid, block, 0, stream>>>(x, weight, bias, out);
}